// Round 1
// baseline (1293.566 us; speedup 1.0000x reference)
//
#include <hip/hip_runtime.h>

// SimpleGraphSAGE: out = mean_agg(x[src]->dst) @ W_l + b_l + x @ W_r
// N=50000 nodes, E=640000 edges, IN=128, HID=256.
// ws layout: agg [N*128] f32, cnt [N] f32.

constexpr int N_NODES = 50000;
constexpr int N_EDGES = 640000;
constexpr int IN_CH   = 128;
constexpr int HID_CH  = 256;

// ---------------------------------------------------------------------------
// Scatter: one thread per (edge, 4-channel group). 32 consecutive threads
// share one edge -> x row read is 128 contiguous floats (coalesced), atomics
// go to 128 contiguous floats of agg[dst].
// ---------------------------------------------------------------------------
__global__ __launch_bounds__(256) void scatter_k(const float* __restrict__ x,
                                                 const int* __restrict__ ei,
                                                 float* __restrict__ agg,
                                                 float* __restrict__ cnt) {
    int t = blockIdx.x * 256 + threadIdx.x;
    if (t >= N_EDGES * 32) return;
    int e    = t >> 5;
    int part = t & 31;
    int src = ei[e];            // row 0 of edge_index
    int dst = ei[N_EDGES + e];  // row 1 of edge_index
    float4 v = reinterpret_cast<const float4*>(x)[src * 32 + part];
    float* a = agg + (size_t)dst * IN_CH + part * 4;
    atomicAdd(a + 0, v.x);
    atomicAdd(a + 1, v.y);
    atomicAdd(a + 2, v.z);
    atomicAdd(a + 3, v.w);
    if (part == 0) atomicAdd(cnt + dst, 1.0f);
}

// ---------------------------------------------------------------------------
// Fused GEMM: A = [mean | x] (K=256), B = [W_l ; W_r] (256x256), + b_l.
// Tile: 64 nodes x 256 cols, BK=32, 256 threads, 4x16 micro-tile/thread.
// LDS: As transposed [32][68] (pad 4 keeps 16B alignment, conflict-free
// broadcast reads), Bs [32][256] (b128 reads are 2-way bank aliased = free).
// ---------------------------------------------------------------------------
__global__ __launch_bounds__(256) void gemm_k(const float* __restrict__ x,
                                              const float* __restrict__ agg,
                                              const float* __restrict__ cnt,
                                              const float* __restrict__ Wl,
                                              const float* __restrict__ bl,
                                              const float* __restrict__ Wr,
                                              float* __restrict__ out) {
    __shared__ float As[32][68];
    __shared__ float Bs[32][256];
    __shared__ float invc[64];

    int tid = threadIdx.x;
    int bm  = blockIdx.x * 64;

    if (tid < 64) {
        int g = bm + tid;
        float c = (g < N_NODES) ? cnt[g] : 1.0f;
        invc[tid] = 1.0f / fmaxf(c, 1.0f);
    }
    __syncthreads();

    float acc[4][16];
#pragma unroll
    for (int i = 0; i < 4; i++)
#pragma unroll
        for (int j = 0; j < 16; j++) acc[i][j] = 0.f;

    int cg = tid & 15;   // col group: cols q*64 + cg*4 + j
    int rg = tid >> 4;   // row group: nodes rg*4 + i

    for (int kc = 0; kc < 8; kc++) {
        // ---- stage A tile: 64 nodes x 32 k (mean for kc<4, x for kc>=4) ----
        const float* Asrc = (kc < 4) ? agg : x;
        int kb = (kc & 3) * 32;
#pragma unroll
        for (int s = 0; s < 2; s++) {
            int idx = tid + s * 256;
            int nl = idx >> 3, f4 = idx & 7;
            int g = bm + nl;
            float4 v = make_float4(0.f, 0.f, 0.f, 0.f);
            if (g < N_NODES)
                v = reinterpret_cast<const float4*>(Asrc + (size_t)g * IN_CH + kb)[f4];
            float sc = (kc < 4) ? invc[nl] : 1.0f;
            As[f4 * 4 + 0][nl] = v.x * sc;
            As[f4 * 4 + 1][nl] = v.y * sc;
            As[f4 * 4 + 2][nl] = v.z * sc;
            As[f4 * 4 + 3][nl] = v.w * sc;
        }
        // ---- stage B tile: 32 k x 256 cols ----
        const float* Bsrc = ((kc < 4) ? Wl : Wr) + (size_t)kb * HID_CH;
#pragma unroll
        for (int s = 0; s < 8; s++) {
            int idx = tid + s * 256;
            int kk = idx >> 6, c4 = idx & 63;
            float4 v = reinterpret_cast<const float4*>(Bsrc + kk * HID_CH)[c4];
            *reinterpret_cast<float4*>(&Bs[kk][c4 * 4]) = v;
        }
        __syncthreads();

#pragma unroll
        for (int kk = 0; kk < 32; kk++) {
            float4 a4 = *reinterpret_cast<const float4*>(&As[kk][rg * 4]);
            float a[4] = {a4.x, a4.y, a4.z, a4.w};
#pragma unroll
            for (int q = 0; q < 4; q++) {
                float4 b4 = *reinterpret_cast<const float4*>(&Bs[kk][q * 64 + cg * 4]);
                float b[4] = {b4.x, b4.y, b4.z, b4.w};
#pragma unroll
                for (int i = 0; i < 4; i++)
#pragma unroll
                    for (int j = 0; j < 4; j++)
                        acc[i][q * 4 + j] = fmaf(a[i], b[j], acc[i][q * 4 + j]);
            }
        }
        __syncthreads();
    }

    // ---- epilogue: + bias, store float4 ----
#pragma unroll
    for (int i = 0; i < 4; i++) {
        int node = bm + rg * 4 + i;
        if (node < N_NODES) {
#pragma unroll
            for (int q = 0; q < 4; q++) {
                int col = q * 64 + cg * 4;
                float4 bb = *reinterpret_cast<const float4*>(bl + col);
                float4 o;
                o.x = acc[i][q * 4 + 0] + bb.x;
                o.y = acc[i][q * 4 + 1] + bb.y;
                o.z = acc[i][q * 4 + 2] + bb.z;
                o.w = acc[i][q * 4 + 3] + bb.w;
                *reinterpret_cast<float4*>(out + (size_t)node * HID_CH + col) = o;
            }
        }
    }
}

extern "C" void kernel_launch(void* const* d_in, const int* in_sizes, int n_in,
                              void* d_out, int out_size, void* d_ws, size_t ws_size,
                              hipStream_t stream) {
    const float* x  = (const float*)d_in[0];
    const int*   ei = (const int*)d_in[1];   // [2, E] int32 (JAX demotes int64)
    const float* Wl = (const float*)d_in[2];
    const float* bl = (const float*)d_in[3];
    const float* Wr = (const float*)d_in[4];
    float* out = (float*)d_out;

    float* agg = (float*)d_ws;                       // [N*128]
    float* cnt = agg + (size_t)N_NODES * IN_CH;      // [N]

    size_t zero_bytes = ((size_t)N_NODES * IN_CH + N_NODES) * sizeof(float);
    hipMemsetAsync(d_ws, 0, zero_bytes, stream);

    int scat_threads = N_EDGES * 32;
    scatter_k<<<(scat_threads + 255) / 256, 256, 0, stream>>>(x, ei, agg, cnt);

    gemm_k<<<(N_NODES + 63) / 64, 256, 0, stream>>>(x, agg, cnt, Wl, bl, Wr, out);
}

// Round 2
// 311.462 us; speedup vs baseline: 4.1532x; 4.1532x over previous
//
#include <hip/hip_runtime.h>

// SimpleGraphSAGE: out = mean_agg(x[src]->dst) @ W_l + b_l + x @ W_r
// N=50000 nodes, E=640000 edges, IN=128, HID=256.
// R2: replace fp32-atomic scatter (1110us, L2 atomic-thrash) with device CSR
// build (counting sort) + wave-per-node gather aggregation (no fp32 atomics).

constexpr int N_NODES = 50000;
constexpr int N_EDGES = 640000;
constexpr int IN_CH   = 128;
constexpr int HID_CH  = 256;
constexpr int SCAN_BLOCKS = (N_NODES + 256) / 256;  // covers i == N_NODES too (196)

// ---------------------------------------------------------------------------
// 1. Histogram of dst
// ---------------------------------------------------------------------------
__global__ __launch_bounds__(256) void hist_k(const int* __restrict__ ei,
                                              int* __restrict__ cnt) {
    int e = blockIdx.x * 256 + threadIdx.x;
    if (e < N_EDGES) atomicAdd(&cnt[ei[N_EDGES + e]], 1);
}

// ---------------------------------------------------------------------------
// Block-wide exclusive scan helper (Hillis-Steele in LDS, 256 threads)
// ---------------------------------------------------------------------------
__device__ inline int block_scan_excl(int v, int tid, int* tmp) {
    tmp[tid] = v;
    __syncthreads();
#pragma unroll
    for (int off = 1; off < 256; off <<= 1) {
        int t = (tid >= off) ? tmp[tid - off] : 0;
        __syncthreads();
        tmp[tid] += t;
        __syncthreads();
    }
    return tmp[tid] - v;  // exclusive
}

// 2a. per-block sums of cnt
__global__ __launch_bounds__(256) void scan1_k(const int* __restrict__ cnt,
                                               int* __restrict__ blockSums) {
    __shared__ int tmp[256];
    int i = blockIdx.x * 256 + threadIdx.x;
    int v = (i < N_NODES) ? cnt[i] : 0;
    block_scan_excl(v, threadIdx.x, tmp);
    if (threadIdx.x == 255) blockSums[blockIdx.x] = tmp[255];
}

// 2b. scan the block sums (single block; SCAN_BLOCKS <= 256)
__global__ __launch_bounds__(256) void scan2_k(int* __restrict__ blockSums,
                                               int* __restrict__ blockOff) {
    __shared__ int tmp[256];
    int tid = threadIdx.x;
    int v = (tid < SCAN_BLOCKS) ? blockSums[tid] : 0;
    int ex = block_scan_excl(v, tid, tmp);
    if (tid < SCAN_BLOCKS) blockOff[tid] = ex;
}

// 2c. full exclusive scan -> row_start, cursor
__global__ __launch_bounds__(256) void scan3_k(const int* __restrict__ cnt,
                                               const int* __restrict__ blockOff,
                                               int* __restrict__ row_start,
                                               int* __restrict__ cursor) {
    __shared__ int tmp[256];
    int i = blockIdx.x * 256 + threadIdx.x;
    int v = (i < N_NODES) ? cnt[i] : 0;
    int ex = block_scan_excl(v, threadIdx.x, tmp);
    int rs = blockOff[blockIdx.x] + ex;
    if (i < N_NODES) {
        row_start[i] = rs;
        cursor[i]    = rs;
    }
    if (i == N_NODES) row_start[N_NODES] = rs;  // == N_EDGES
}

// ---------------------------------------------------------------------------
// 3. Permute src into dst-sorted order
// ---------------------------------------------------------------------------
__global__ __launch_bounds__(256) void permute_k(const int* __restrict__ ei,
                                                 int* __restrict__ cursor,
                                                 int* __restrict__ sorted_src) {
    int e = blockIdx.x * 256 + threadIdx.x;
    if (e >= N_EDGES) return;
    int dst = ei[N_EDGES + e];
    int pos = atomicAdd(&cursor[dst], 1);
    sorted_src[pos] = ei[e];
}

// ---------------------------------------------------------------------------
// 4. Aggregate: one wave per node, lane l holds channels {2l, 2l+1}.
//    Writes the MEAN directly.
// ---------------------------------------------------------------------------
__global__ __launch_bounds__(256) void agg_k(const float* __restrict__ x,
                                             const int* __restrict__ row_start,
                                             const int* __restrict__ sorted_src,
                                             float* __restrict__ mean) {
    int wid  = (blockIdx.x * 256 + threadIdx.x) >> 6;  // node id
    int lane = threadIdx.x & 63;
    if (wid >= N_NODES) return;
    int beg = row_start[wid];
    int end = row_start[wid + 1];
    const float2* xr = reinterpret_cast<const float2*>(x);
    float sx = 0.f, sy = 0.f;
    int i = beg;
    // unroll by 2 for load ILP
    for (; i + 1 < end; i += 2) {
        int s0 = sorted_src[i];
        int s1 = sorted_src[i + 1];
        float2 v0 = xr[(size_t)s0 * 64 + lane];
        float2 v1 = xr[(size_t)s1 * 64 + lane];
        sx += v0.x + v1.x;
        sy += v0.y + v1.y;
    }
    if (i < end) {
        int s0 = sorted_src[i];
        float2 v0 = xr[(size_t)s0 * 64 + lane];
        sx += v0.x;
        sy += v0.y;
    }
    float inv = (end > beg) ? 1.0f / (float)(end - beg) : 0.0f;
    reinterpret_cast<float2*>(mean)[(size_t)wid * 64 + lane] =
        make_float2(sx * inv, sy * inv);
}

// ---------------------------------------------------------------------------
// 5. Fused GEMM: A = [mean | x] (K=256), B = [W_l ; W_r], + b_l.
//    Tile: 64 nodes x 256 cols, BK=32, 256 threads, 4x16 micro-tile/thread.
// ---------------------------------------------------------------------------
__global__ __launch_bounds__(256) void gemm_k(const float* __restrict__ x,
                                              const float* __restrict__ mean,
                                              const float* __restrict__ Wl,
                                              const float* __restrict__ bl,
                                              const float* __restrict__ Wr,
                                              float* __restrict__ out) {
    __shared__ float As[32][68];
    __shared__ float Bs[32][256];

    int tid = threadIdx.x;
    int bm  = blockIdx.x * 64;

    float acc[4][16];
#pragma unroll
    for (int i = 0; i < 4; i++)
#pragma unroll
        for (int j = 0; j < 16; j++) acc[i][j] = 0.f;

    int cg = tid & 15;   // col group: cols q*64 + cg*4 + j
    int rg = tid >> 4;   // row group: nodes rg*4 + i

    for (int kc = 0; kc < 8; kc++) {
        const float* Asrc = (kc < 4) ? mean : x;
        int kb = (kc & 3) * 32;
#pragma unroll
        for (int s = 0; s < 2; s++) {
            int idx = tid + s * 256;
            int nl = idx >> 3, f4 = idx & 7;
            int g = bm + nl;
            float4 v = make_float4(0.f, 0.f, 0.f, 0.f);
            if (g < N_NODES)
                v = reinterpret_cast<const float4*>(Asrc + (size_t)g * IN_CH + kb)[f4];
            As[f4 * 4 + 0][nl] = v.x;
            As[f4 * 4 + 1][nl] = v.y;
            As[f4 * 4 + 2][nl] = v.z;
            As[f4 * 4 + 3][nl] = v.w;
        }
        const float* Bsrc = ((kc < 4) ? Wl : Wr) + (size_t)kb * HID_CH;
#pragma unroll
        for (int s = 0; s < 8; s++) {
            int idx = tid + s * 256;
            int kk = idx >> 6, c4 = idx & 63;
            float4 v = reinterpret_cast<const float4*>(Bsrc + kk * HID_CH)[c4];
            *reinterpret_cast<float4*>(&Bs[kk][c4 * 4]) = v;
        }
        __syncthreads();

#pragma unroll
        for (int kk = 0; kk < 32; kk++) {
            float4 a4 = *reinterpret_cast<const float4*>(&As[kk][rg * 4]);
            float a[4] = {a4.x, a4.y, a4.z, a4.w};
#pragma unroll
            for (int q = 0; q < 4; q++) {
                float4 b4 = *reinterpret_cast<const float4*>(&Bs[kk][q * 64 + cg * 4]);
                float b[4] = {b4.x, b4.y, b4.z, b4.w};
#pragma unroll
                for (int i = 0; i < 4; i++)
#pragma unroll
                    for (int j = 0; j < 4; j++)
                        acc[i][q * 4 + j] = fmaf(a[i], b[j], acc[i][q * 4 + j]);
            }
        }
        __syncthreads();
    }

#pragma unroll
    for (int i = 0; i < 4; i++) {
        int node = bm + rg * 4 + i;
        if (node < N_NODES) {
#pragma unroll
            for (int q = 0; q < 4; q++) {
                int col = q * 64 + cg * 4;
                float4 bb = *reinterpret_cast<const float4*>(bl + col);
                float4 o;
                o.x = acc[i][q * 4 + 0] + bb.x;
                o.y = acc[i][q * 4 + 1] + bb.y;
                o.z = acc[i][q * 4 + 2] + bb.z;
                o.w = acc[i][q * 4 + 3] + bb.w;
                *reinterpret_cast<float4*>(out + (size_t)node * HID_CH + col) = o;
            }
        }
    }
}

extern "C" void kernel_launch(void* const* d_in, const int* in_sizes, int n_in,
                              void* d_out, int out_size, void* d_ws, size_t ws_size,
                              hipStream_t stream) {
    const float* x  = (const float*)d_in[0];
    const int*   ei = (const int*)d_in[1];   // [2, E] int32
    const float* Wl = (const float*)d_in[2];
    const float* bl = (const float*)d_in[3];
    const float* Wr = (const float*)d_in[4];
    float* out = (float*)d_out;

    // ws layout
    float* mean       = (float*)d_ws;                          // N*128 f32
    int*   cnt        = (int*)(mean + (size_t)N_NODES * IN_CH); // N
    int*   row_start  = cnt + N_NODES;                          // N+1
    int*   cursor     = row_start + N_NODES + 1;                // N
    int*   blockSums  = cursor + N_NODES;                       // 256
    int*   blockOff   = blockSums + 256;                        // 256
    int*   sorted_src = blockOff + 256;                         // E

    hipMemsetAsync(cnt, 0, N_NODES * sizeof(int), stream);

    hist_k<<<(N_EDGES + 255) / 256, 256, 0, stream>>>(ei, cnt);
    scan1_k<<<SCAN_BLOCKS, 256, 0, stream>>>(cnt, blockSums);
    scan2_k<<<1, 256, 0, stream>>>(blockSums, blockOff);
    scan3_k<<<SCAN_BLOCKS, 256, 0, stream>>>(cnt, blockOff, row_start, cursor);
    permute_k<<<(N_EDGES + 255) / 256, 256, 0, stream>>>(ei, cursor, sorted_src);
    agg_k<<<(N_NODES * 64 + 255) / 256, 256, 0, stream>>>(x, row_start, sorted_src, mean);
    gemm_k<<<(N_NODES + 63) / 64, 256, 0, stream>>>(x, mean, Wl, bl, Wr, out);
}

// Round 3
// 229.193 us; speedup vs baseline: 5.6440x; 1.3590x over previous
//
#include <hip/hip_runtime.h>

// SimpleGraphSAGE: out = mean_agg(x[src]->dst) @ W_l + b_l + x @ W_r
// N=50000, E=640000, IN=128, HID=256.
// R3: bf16 everywhere past the prep stage.
//   - Abf [N][256] bf16 in ws: cols 0..127 = mean (written by agg_k),
//     cols 128..255 = bf16(x) (written by prep_x_k, read by agg_k gather).
//   - Wimg: W=[W_l;W_r] pre-tiled bf16, B^T layout per 32-k block so GEMM
//     B-staging is contiguous 64B/thread.
//   - gemm_k: 64x256 tile, 4 waves, mfma_f32_16x16x32_bf16, LDS rows padded
//     to 40 bf16 (80B) -> b128 frag reads at uniform 8/bank-group floor.

constexpr int N_NODES = 50000;
constexpr int N_EDGES = 640000;
constexpr int IN_CH   = 128;
constexpr int HID_CH  = 256;
constexpr int SCAN_BLOCKS = (N_NODES + 256) / 256;  // 196, covers i==N_NODES

typedef __attribute__((ext_vector_type(8))) short short8;
typedef __attribute__((ext_vector_type(4))) float f32x4;

__device__ inline unsigned short f2bf(float f) {
    unsigned int u = __float_as_uint(f);
    u += 0x7fff + ((u >> 16) & 1);  // RNE
    return (unsigned short)(u >> 16);
}
__device__ inline float bf2f(unsigned int s) {
    return __uint_as_float(s << 16);
}

// ---------------------------------------------------------------------------
// prep_x_k: Abf[row][128+c] = bf16(x[row][c]); one thread per 2 channels.
// ---------------------------------------------------------------------------
__global__ __launch_bounds__(256) void prep_x_k(const float* __restrict__ x,
                                                unsigned int* __restrict__ Abf_u) {
    int t = blockIdx.x * 256 + threadIdx.x;       // t < N*64 exactly
    float2 v = reinterpret_cast<const float2*>(x)[t];
    unsigned int p = (unsigned int)f2bf(v.x) | ((unsigned int)f2bf(v.y) << 16);
    int row = t >> 6, l = t & 63;
    Abf_u[(size_t)row * 128 + 64 + l] = p;
}

// ---------------------------------------------------------------------------
// wprep_k: Wimg[kc][n][kk] = bf16(Wcat[kc*32+kk][n]), Wcat = [W_l ; W_r].
// ---------------------------------------------------------------------------
__global__ __launch_bounds__(256) void wprep_k(const float* __restrict__ Wl,
                                               const float* __restrict__ Wr,
                                               unsigned short* __restrict__ Wimg) {
    int t = blockIdx.x * 256 + threadIdx.x;       // 65536
    int k = t >> 8, n = t & 255;
    float v = (k < 128) ? Wl[k * 256 + n] : Wr[(k - 128) * 256 + n];
    Wimg[(size_t)(k >> 5) * 8192 + n * 32 + (k & 31)] = f2bf(v);
}

// ---------------------------------------------------------------------------
// CSR build: histogram -> scan -> permute
// ---------------------------------------------------------------------------
__global__ __launch_bounds__(256) void hist_k(const int* __restrict__ ei,
                                              int* __restrict__ cnt) {
    int e = blockIdx.x * 256 + threadIdx.x;
    if (e < N_EDGES) atomicAdd(&cnt[ei[N_EDGES + e]], 1);
}

__device__ inline int block_scan_excl(int v, int tid, int* tmp) {
    tmp[tid] = v;
    __syncthreads();
#pragma unroll
    for (int off = 1; off < 256; off <<= 1) {
        int t = (tid >= off) ? tmp[tid - off] : 0;
        __syncthreads();
        tmp[tid] += t;
        __syncthreads();
    }
    return tmp[tid] - v;
}

__global__ __launch_bounds__(256) void scan1_k(const int* __restrict__ cnt,
                                               int* __restrict__ blockSums) {
    __shared__ int tmp[256];
    int i = blockIdx.x * 256 + threadIdx.x;
    int v = (i < N_NODES) ? cnt[i] : 0;
    block_scan_excl(v, threadIdx.x, tmp);
    if (threadIdx.x == 255) blockSums[blockIdx.x] = tmp[255];
}

__global__ __launch_bounds__(256) void scan2_k(int* __restrict__ blockSums,
                                               int* __restrict__ blockOff) {
    __shared__ int tmp[256];
    int tid = threadIdx.x;
    int v = (tid < SCAN_BLOCKS) ? blockSums[tid] : 0;
    int ex = block_scan_excl(v, tid, tmp);
    if (tid < SCAN_BLOCKS) blockOff[tid] = ex;
}

__global__ __launch_bounds__(256) void scan3_k(const int* __restrict__ cnt,
                                               const int* __restrict__ blockOff,
                                               int* __restrict__ row_start,
                                               int* __restrict__ cursor) {
    __shared__ int tmp[256];
    int i = blockIdx.x * 256 + threadIdx.x;
    int v = (i < N_NODES) ? cnt[i] : 0;
    int ex = block_scan_excl(v, threadIdx.x, tmp);
    int rs = blockOff[blockIdx.x] + ex;
    if (i < N_NODES) {
        row_start[i] = rs;
        cursor[i]    = rs;
    }
    if (i == N_NODES) row_start[N_NODES] = rs;
}

__global__ __launch_bounds__(256) void permute_k(const int* __restrict__ ei,
                                                 int* __restrict__ cursor,
                                                 int* __restrict__ sorted_src) {
    int e = blockIdx.x * 256 + threadIdx.x;
    if (e >= N_EDGES) return;
    int dst = ei[N_EDGES + e];
    int pos = atomicAdd(&cursor[dst], 1);
    sorted_src[pos] = ei[e];
}

// ---------------------------------------------------------------------------
// agg_k: one wave per node; lane l sums channels {2l,2l+1} over neighbors,
// reading the bf16 x-copy in Abf's second half; writes mean (bf16) to first.
// ---------------------------------------------------------------------------
__global__ __launch_bounds__(256) void agg_k(const int* __restrict__ row_start,
                                             const int* __restrict__ sorted_src,
                                             unsigned int* __restrict__ Abf_u) {
    int wid  = (blockIdx.x * 256 + threadIdx.x) >> 6;  // node, < N exactly
    int lane = threadIdx.x & 63;
    int beg = row_start[wid];
    int end = row_start[wid + 1];
    float sx = 0.f, sy = 0.f;
    int i = beg;
    for (; i + 1 < end; i += 2) {
        int s0 = sorted_src[i];
        int s1 = sorted_src[i + 1];
        unsigned int v0 = Abf_u[(size_t)s0 * 128 + 64 + lane];
        unsigned int v1 = Abf_u[(size_t)s1 * 128 + 64 + lane];
        sx += bf2f(v0 & 0xffffu) + bf2f(v1 & 0xffffu);
        sy += bf2f(v0 >> 16) + bf2f(v1 >> 16);
    }
    if (i < end) {
        unsigned int v0 = Abf_u[(size_t)sorted_src[i] * 128 + 64 + lane];
        sx += bf2f(v0 & 0xffffu);
        sy += bf2f(v0 >> 16);
    }
    float inv = (end > beg) ? 1.0f / (float)(end - beg) : 0.0f;
    unsigned int p = (unsigned int)f2bf(sx * inv) |
                     ((unsigned int)f2bf(sy * inv) << 16);
    Abf_u[(size_t)wid * 128 + lane] = p;
}

// ---------------------------------------------------------------------------
// gemm_k: out[N][256] = Abf[N][256] @ Wcat[256][256] + bl, bf16 MFMA.
// Block: 256 thr = 4 waves, tile 64 rows x 256 cols; wave w owns cols
// [64w,64w+64) as 4x4 grid of 16x16 tiles. K loop: 8 steps of 32.
// ---------------------------------------------------------------------------
__global__ __launch_bounds__(256) void gemm_k(const unsigned short* __restrict__ Abf,
                                              const unsigned short* __restrict__ Wimg,
                                              const float* __restrict__ bl,
                                              float* __restrict__ out) {
    __shared__ unsigned short As[64 * 40];    // rows padded to 40 bf16 (80B)
    __shared__ unsigned short Bs[256 * 40];

    int tid  = threadIdx.x;
    int w    = tid >> 6;
    int lane = tid & 63;
    int m15  = lane & 15;
    int quad = lane >> 4;
    int bm   = blockIdx.x * 64;

    f32x4 zero4 = {0.f, 0.f, 0.f, 0.f};
    f32x4 acc[4][4];
#pragma unroll
    for (int rt = 0; rt < 4; rt++)
#pragma unroll
        for (int ct = 0; ct < 4; ct++) acc[rt][ct] = zero4;

    for (int kc = 0; kc < 8; kc++) {
        // stage A: thread t -> row t>>2, 16B chunk q=t&3 (coalesced 4KB)
        {
            int row = tid >> 2, q = tid & 3;
            int grow = bm + row;
            short8 v = {0, 0, 0, 0, 0, 0, 0, 0};
            if (grow < N_NODES)
                v = *reinterpret_cast<const short8*>(
                        Abf + (size_t)grow * 256 + kc * 32 + q * 8);
            *reinterpret_cast<short8*>(As + row * 40 + q * 8) = v;
        }
        // stage B: thread t copies 64B row n=t of this k-block (coalesced)
        {
            const unsigned short* src = Wimg + (size_t)kc * 8192 + tid * 32;
#pragma unroll
            for (int s = 0; s < 4; s++) {
                short8 v = *reinterpret_cast<const short8*>(src + s * 8);
                *reinterpret_cast<short8*>(Bs + tid * 40 + s * 8) = v;
            }
        }
        __syncthreads();

        short8 Af[4], Bf[4];
#pragma unroll
        for (int rt = 0; rt < 4; rt++)
            Af[rt] = *reinterpret_cast<const short8*>(
                         As + (rt * 16 + m15) * 40 + quad * 8);
#pragma unroll
        for (int ct = 0; ct < 4; ct++)
            Bf[ct] = *reinterpret_cast<const short8*>(
                         Bs + (w * 64 + ct * 16 + m15) * 40 + quad * 8);
#pragma unroll
        for (int rt = 0; rt < 4; rt++)
#pragma unroll
            for (int ct = 0; ct < 4; ct++)
                acc[rt][ct] = __builtin_amdgcn_mfma_f32_16x16x32_bf16(
                    Af[rt], Bf[ct], acc[rt][ct], 0, 0, 0);
        __syncthreads();
    }

    // epilogue: C/D layout col=lane&15, row=quad*4+reg
    float bias[4];
#pragma unroll
    for (int ct = 0; ct < 4; ct++) bias[ct] = bl[w * 64 + ct * 16 + m15];
#pragma unroll
    for (int rt = 0; rt < 4; rt++) {
        int rb = bm + rt * 16 + quad * 4;
#pragma unroll
        for (int r = 0; r < 4; r++) {
            int row = rb + r;
            if (row < N_NODES) {
#pragma unroll
                for (int ct = 0; ct < 4; ct++)
                    out[(size_t)row * 256 + w * 64 + ct * 16 + m15] =
                        acc[rt][ct][r] + bias[ct];
            }
        }
    }
}

extern "C" void kernel_launch(void* const* d_in, const int* in_sizes, int n_in,
                              void* d_out, int out_size, void* d_ws, size_t ws_size,
                              hipStream_t stream) {
    const float* x  = (const float*)d_in[0];
    const int*   ei = (const int*)d_in[1];   // [2, E] int32
    const float* Wl = (const float*)d_in[2];
    const float* bl = (const float*)d_in[3];
    const float* Wr = (const float*)d_in[4];
    float* out = (float*)d_out;

    // ws layout
    unsigned short* Abf  = (unsigned short*)d_ws;              // N*256 bf16
    unsigned short* Wimg = Abf + (size_t)N_NODES * 256;        // 65536 bf16
    int* cnt        = (int*)(Wimg + 65536);                    // N
    int* row_start  = cnt + N_NODES;                           // N+1
    int* cursor     = row_start + N_NODES + 1;                 // N
    int* blockSums  = cursor + N_NODES;                        // 256
    int* blockOff   = blockSums + 256;                         // 256
    int* sorted_src = blockOff + 256;                          // E

    hipMemsetAsync(cnt, 0, N_NODES * sizeof(int), stream);

    prep_x_k<<<(N_NODES * 64) / 256, 256, 0, stream>>>(x, (unsigned int*)Abf);
    wprep_k<<<256, 256, 0, stream>>>(Wl, Wr, Wimg);
    hist_k<<<(N_EDGES + 255) / 256, 256, 0, stream>>>(ei, cnt);
    scan1_k<<<SCAN_BLOCKS, 256, 0, stream>>>(cnt, blockSums);
    scan2_k<<<1, 256, 0, stream>>>(blockSums, blockOff);
    scan3_k<<<SCAN_BLOCKS, 256, 0, stream>>>(cnt, blockOff, row_start, cursor);
    permute_k<<<(N_EDGES + 255) / 256, 256, 0, stream>>>(ei, cursor, sorted_src);
    agg_k<<<(N_NODES * 64) / 256, 256, 0, stream>>>(row_start, sorted_src,
                                                    (unsigned int*)Abf);
    gemm_k<<<(N_NODES + 63) / 64, 256, 0, stream>>>(Abf, Wimg, bl, out);
}

// Round 4
// 203.950 us; speedup vs baseline: 6.3426x; 1.1238x over previous
//
#include <hip/hip_runtime.h>

// SimpleGraphSAGE: out = mean_agg(x[src]->dst) @ W_l + b_l + x @ W_r
// N=50000, E=640000, IN=128, HID=256.
// R4: (a) agg_k re-layout: 16 lanes x 16B per row -> one load inst covers 4
//     edges, unroll x2 = 8 edges (2KB) in flight per wave (was 2 x 256B);
//     cross-edge-group reduce via shfl_xor(16/32).
//     (b) fuse prep_x+wprep+hist into one kernel; merge scan2 into scan3.

constexpr int N_NODES = 50000;
constexpr int N_EDGES = 640000;
constexpr int IN_CH   = 128;
constexpr int HID_CH  = 256;
constexpr int SCAN_BLOCKS = (N_NODES + 256) / 256;  // 196, covers i==N_NODES

constexpr int HIST_BLOCKS  = N_EDGES / 1024;        // 625, thread handles 4 edges
constexpr int PREPX_BLOCKS = N_NODES * 32 / 256;    // 6250, thread = 4 channels
constexpr int WPREP_BLOCKS = 256;                   // 65536 weight elems

typedef __attribute__((ext_vector_type(8))) short short8;
typedef __attribute__((ext_vector_type(4))) float f32x4;

__device__ inline unsigned short f2bf(float f) {
    unsigned int u = __float_as_uint(f);
    u += 0x7fff + ((u >> 16) & 1);  // RNE
    return (unsigned short)(u >> 16);
}
__device__ inline float bf2f(unsigned int s) {
    return __uint_as_float(s << 16);
}

// ---------------------------------------------------------------------------
// prep_k: block-range fused  [hist | x->bf16 | W->bf16 tiled]
// ---------------------------------------------------------------------------
__global__ __launch_bounds__(256) void prep_k(const float* __restrict__ x,
                                              const int* __restrict__ ei,
                                              const float* __restrict__ Wl,
                                              const float* __restrict__ Wr,
                                              unsigned int* __restrict__ Abf_u,
                                              unsigned short* __restrict__ Wimg,
                                              int* __restrict__ cnt) {
    int bid = blockIdx.x, tid = threadIdx.x;
    if (bid < HIST_BLOCKS) {
        int base = bid * 1024 + tid;
#pragma unroll
        for (int k = 0; k < 4; k++)
            atomicAdd(&cnt[ei[N_EDGES + base + k * 256]], 1);
    } else if (bid < HIST_BLOCKS + PREPX_BLOCKS) {
        int t = (bid - HIST_BLOCKS) * 256 + tid;          // < N*32
        float4 v = reinterpret_cast<const float4*>(x)[t];
        unsigned int p0 = (unsigned int)f2bf(v.x) | ((unsigned int)f2bf(v.y) << 16);
        unsigned int p1 = (unsigned int)f2bf(v.z) | ((unsigned int)f2bf(v.w) << 16);
        int row = t >> 5, c = t & 31;
        reinterpret_cast<uint2*>(Abf_u)[(size_t)row * 64 + 32 + c] =
            make_uint2(p0, p1);
    } else {
        int t = (bid - HIST_BLOCKS - PREPX_BLOCKS) * 256 + tid;  // < 65536
        int k = t >> 8, n = t & 255;
        float v = (k < 128) ? Wl[k * 256 + n] : Wr[(k - 128) * 256 + n];
        Wimg[(size_t)(k >> 5) * 8192 + n * 32 + (k & 31)] = f2bf(v);
    }
}

// ---------------------------------------------------------------------------
// CSR build: scan + permute
// ---------------------------------------------------------------------------
__device__ inline int block_scan_excl(int v, int tid, int* tmp) {
    tmp[tid] = v;
    __syncthreads();
#pragma unroll
    for (int off = 1; off < 256; off <<= 1) {
        int t = (tid >= off) ? tmp[tid - off] : 0;
        __syncthreads();
        tmp[tid] += t;
        __syncthreads();
    }
    return tmp[tid] - v;
}

__global__ __launch_bounds__(256) void scan1_k(const int* __restrict__ cnt,
                                               int* __restrict__ blockSums) {
    __shared__ int tmp[256];
    int i = blockIdx.x * 256 + threadIdx.x;
    int v = (i < N_NODES) ? cnt[i] : 0;
    block_scan_excl(v, threadIdx.x, tmp);
    if (threadIdx.x == 255) blockSums[blockIdx.x] = tmp[255];
}

// scan23: each block reduces its own prefix of blockSums, then local scan.
__global__ __launch_bounds__(256) void scan23_k(const int* __restrict__ cnt,
                                                const int* __restrict__ blockSums,
                                                int* __restrict__ row_start,
                                                int* __restrict__ cursor) {
    __shared__ int red[256];
    __shared__ int tmp[256];
    int tid = threadIdx.x;
    int bv = (tid < (int)blockIdx.x) ? blockSums[tid] : 0;  // blockIdx < 256
    red[tid] = bv;
    __syncthreads();
#pragma unroll
    for (int off = 128; off > 0; off >>= 1) {
        if (tid < off) red[tid] += red[tid + off];
        __syncthreads();
    }
    int boff = red[0];
    int i = blockIdx.x * 256 + tid;
    int v = (i < N_NODES) ? cnt[i] : 0;
    int ex = block_scan_excl(v, tid, tmp);
    int rs = boff + ex;
    if (i < N_NODES) {
        row_start[i] = rs;
        cursor[i]    = rs;
    }
    if (i == N_NODES) row_start[N_NODES] = rs;
}

__global__ __launch_bounds__(256) void permute_k(const int* __restrict__ ei,
                                                 int* __restrict__ cursor,
                                                 int* __restrict__ sorted_src) {
    int e = blockIdx.x * 256 + threadIdx.x;
    if (e >= N_EDGES) return;
    int dst = ei[N_EDGES + e];
    int pos = atomicAdd(&cursor[dst], 1);
    sorted_src[pos] = ei[e];
}

// ---------------------------------------------------------------------------
// agg_k: one wave per node. Lane = (g, sub): g = edge subgroup (0..3),
// sub = 16B chunk of the 256B bf16 row. One load inst = 4 edges; unroll x2
// = 8 edges / 2KB in flight. shfl_xor(16/32) folds the 4 groups.
// ---------------------------------------------------------------------------
__global__ __launch_bounds__(256) void agg_k(const int* __restrict__ row_start,
                                             const int* __restrict__ sorted_src,
                                             unsigned int* __restrict__ Abf_u) {
    int wid  = (blockIdx.x * 256 + threadIdx.x) >> 6;  // node, < N exactly
    int lane = threadIdx.x & 63;
    int g    = lane >> 4;
    int sub  = lane & 15;
    int beg = row_start[wid];
    int end = row_start[wid + 1];
    const uint4* X = reinterpret_cast<const uint4*>(Abf_u);  // row = 32 uint4

    float s[8];
#pragma unroll
    for (int j = 0; j < 8; j++) s[j] = 0.f;

    for (int i = beg; i < end; i += 8) {
        int e0 = i + g;
        int e1 = i + 4 + g;
        uint4 v0 = make_uint4(0, 0, 0, 0), v1 = make_uint4(0, 0, 0, 0);
        if (e0 < end) v0 = X[(size_t)sorted_src[e0] * 32 + 16 + sub];
        if (e1 < end) v1 = X[(size_t)sorted_src[e1] * 32 + 16 + sub];
        s[0] += bf2f(v0.x & 0xffffu) + bf2f(v1.x & 0xffffu);
        s[1] += bf2f(v0.x >> 16)     + bf2f(v1.x >> 16);
        s[2] += bf2f(v0.y & 0xffffu) + bf2f(v1.y & 0xffffu);
        s[3] += bf2f(v0.y >> 16)     + bf2f(v1.y >> 16);
        s[4] += bf2f(v0.z & 0xffffu) + bf2f(v1.z & 0xffffu);
        s[5] += bf2f(v0.z >> 16)     + bf2f(v1.z >> 16);
        s[6] += bf2f(v0.w & 0xffffu) + bf2f(v1.w & 0xffffu);
        s[7] += bf2f(v0.w >> 16)     + bf2f(v1.w >> 16);
    }

#pragma unroll
    for (int m = 16; m <= 32; m <<= 1)
#pragma unroll
        for (int j = 0; j < 8; j++) s[j] += __shfl_xor(s[j], m, 64);

    if (g == 0) {
        float inv = (end > beg) ? 1.0f / (float)(end - beg) : 0.0f;
        uint4 o;
        o.x = (unsigned int)f2bf(s[0] * inv) | ((unsigned int)f2bf(s[1] * inv) << 16);
        o.y = (unsigned int)f2bf(s[2] * inv) | ((unsigned int)f2bf(s[3] * inv) << 16);
        o.z = (unsigned int)f2bf(s[4] * inv) | ((unsigned int)f2bf(s[5] * inv) << 16);
        o.w = (unsigned int)f2bf(s[6] * inv) | ((unsigned int)f2bf(s[7] * inv) << 16);
        reinterpret_cast<uint4*>(Abf_u)[(size_t)wid * 32 + sub] = o;
    }
}

// ---------------------------------------------------------------------------
// gemm_k: out[N][256] = Abf[N][256] @ Wcat[256][256] + bl, bf16 MFMA.
// ---------------------------------------------------------------------------
__global__ __launch_bounds__(256) void gemm_k(const unsigned short* __restrict__ Abf,
                                              const unsigned short* __restrict__ Wimg,
                                              const float* __restrict__ bl,
                                              float* __restrict__ out) {
    __shared__ unsigned short As[64 * 40];    // rows padded to 40 bf16 (80B)
    __shared__ unsigned short Bs[256 * 40];

    int tid  = threadIdx.x;
    int w    = tid >> 6;
    int lane = tid & 63;
    int m15  = lane & 15;
    int quad = lane >> 4;
    int bm   = blockIdx.x * 64;

    f32x4 zero4 = {0.f, 0.f, 0.f, 0.f};
    f32x4 acc[4][4];
#pragma unroll
    for (int rt = 0; rt < 4; rt++)
#pragma unroll
        for (int ct = 0; ct < 4; ct++) acc[rt][ct] = zero4;

    for (int kc = 0; kc < 8; kc++) {
        {
            int row = tid >> 2, q = tid & 3;
            int grow = bm + row;
            short8 v = {0, 0, 0, 0, 0, 0, 0, 0};
            if (grow < N_NODES)
                v = *reinterpret_cast<const short8*>(
                        Abf + (size_t)grow * 256 + kc * 32 + q * 8);
            *reinterpret_cast<short8*>(As + row * 40 + q * 8) = v;
        }
        {
            const unsigned short* src = Wimg + (size_t)kc * 8192 + tid * 32;
#pragma unroll
            for (int s = 0; s < 4; s++) {
                short8 v = *reinterpret_cast<const short8*>(src + s * 8);
                *reinterpret_cast<short8*>(Bs + tid * 40 + s * 8) = v;
            }
        }
        __syncthreads();

        short8 Af[4], Bf[4];
#pragma unroll
        for (int rt = 0; rt < 4; rt++)
            Af[rt] = *reinterpret_cast<const short8*>(
                         As + (rt * 16 + m15) * 40 + quad * 8);
#pragma unroll
        for (int ct = 0; ct < 4; ct++)
            Bf[ct] = *reinterpret_cast<const short8*>(
                         Bs + (w * 64 + ct * 16 + m15) * 40 + quad * 8);
#pragma unroll
        for (int rt = 0; rt < 4; rt++)
#pragma unroll
            for (int ct = 0; ct < 4; ct++)
                acc[rt][ct] = __builtin_amdgcn_mfma_f32_16x16x32_bf16(
                    Af[rt], Bf[ct], acc[rt][ct], 0, 0, 0);
        __syncthreads();
    }

    float bias[4];
#pragma unroll
    for (int ct = 0; ct < 4; ct++) bias[ct] = bl[w * 64 + ct * 16 + m15];
#pragma unroll
    for (int rt = 0; rt < 4; rt++) {
        int rb = bm + rt * 16 + quad * 4;
#pragma unroll
        for (int r = 0; r < 4; r++) {
            int row = rb + r;
            if (row < N_NODES) {
#pragma unroll
                for (int ct = 0; ct < 4; ct++)
                    out[(size_t)row * 256 + w * 64 + ct * 16 + m15] =
                        acc[rt][ct][r] + bias[ct];
            }
        }
    }
}

extern "C" void kernel_launch(void* const* d_in, const int* in_sizes, int n_in,
                              void* d_out, int out_size, void* d_ws, size_t ws_size,
                              hipStream_t stream) {
    const float* x  = (const float*)d_in[0];
    const int*   ei = (const int*)d_in[1];   // [2, E] int32
    const float* Wl = (const float*)d_in[2];
    const float* bl = (const float*)d_in[3];
    const float* Wr = (const float*)d_in[4];
    float* out = (float*)d_out;

    // ws layout
    unsigned short* Abf  = (unsigned short*)d_ws;              // N*256 bf16
    unsigned short* Wimg = Abf + (size_t)N_NODES * 256;        // 65536 bf16
    int* cnt        = (int*)(Wimg + 65536);                    // N
    int* row_start  = cnt + N_NODES;                           // N+1
    int* cursor     = row_start + N_NODES + 1;                 // N
    int* blockSums  = cursor + N_NODES;                        // 256
    int* sorted_src = blockSums + 256;                         // E

    hipMemsetAsync(cnt, 0, N_NODES * sizeof(int), stream);

    prep_k<<<HIST_BLOCKS + PREPX_BLOCKS + WPREP_BLOCKS, 256, 0, stream>>>(
        x, ei, Wl, Wr, (unsigned int*)Abf, Wimg, cnt);
    scan1_k<<<SCAN_BLOCKS, 256, 0, stream>>>(cnt, blockSums);
    scan23_k<<<SCAN_BLOCKS, 256, 0, stream>>>(cnt, blockSums, row_start, cursor);
    permute_k<<<(N_EDGES + 255) / 256, 256, 0, stream>>>(ei, cursor, sorted_src);
    agg_k<<<(N_NODES * 64) / 256, 256, 0, stream>>>(row_start, sorted_src,
                                                    (unsigned int*)Abf);
    gemm_k<<<(N_NODES + 63) / 64, 256, 0, stream>>>(Abf, Wimg, bl, out);
}